// Round 23
// baseline (113.681 us; speedup 1.0000x reference)
//
#include <hip/hip_runtime.h>
#include <hip/hip_bf16.h>
#include <math.h>

// Problem constants
constexpr int Bn     = 16;    // batch
constexpr int Cc     = 384;   // channels
constexpr int Nn     = 1024;  // tokens (32*32)
constexpr int NHEADS = 8;
constexpr int HD     = 48;    // head dim
constexpr float SCALE = 0.14433756729740643f; // 48^-0.5
constexpr float SCL2  = 0.14433756729740643f * 1.4426950408889634f; // SCALE*log2(e)

using bf16x8 = __attribute__((ext_vector_type(8))) short;
using bf16x4 = __attribute__((ext_vector_type(4))) short;
using f32x4  = __attribute__((ext_vector_type(4))) float;

__device__ inline short f2b(float f) {
    __hip_bfloat16 h = __float2bfloat16(f);
    return *reinterpret_cast<short*>(&h);
}

// async global->LDS, 16B per lane; LDS dest = wave-uniform base + lane*16B
__device__ __forceinline__ void gload16(const short* g, short* l) {
    __builtin_amdgcn_global_load_lds(
        (const __attribute__((address_space(1))) void*)(g),
        (__attribute__((address_space(3))) void*)(l),
        16, 0, 0);
}

// ---------------------------------------------------------------------------
// Fused fp32 -> bf16 cast for BOTH weight tensors.
// ---------------------------------------------------------------------------
__global__ __launch_bounds__(256) void conv_cast2(const float* __restrict__ in1,
                                                  short* __restrict__ hi1, int n1,
                                                  const float* __restrict__ in2,
                                                  short* __restrict__ hi2, int n2)
{
    int u = blockIdx.x * 256 + threadIdx.x;
    const float* in; short* hi; int i;
    if (u * 4 < n1) { in = in1; hi = hi1; i = u * 4; }
    else {
        i = u * 4 - n1;
        if (i >= n2) return;
        in = in2; hi = hi2;
    }
    float4 v = *reinterpret_cast<const float4*>(&in[i]);
    bf16x4 h = { f2b(v.x), f2b(v.y), f2b(v.z), f2b(v.w) };
    *reinterpret_cast<bf16x4*>(&hi[i]) = h;
}

// ---------------------------------------------------------------------------
// x (B, C, N) fp32 -> x^T (B, N, C) bf16.  64x64 tile via LDS.
// ---------------------------------------------------------------------------
__global__ __launch_bounds__(256) void prep_xt(const float* __restrict__ x,
                                               short* __restrict__ xt)
{
    const int b  = blockIdx.z;
    const int c0 = blockIdx.y * 64;
    const int n0 = blockIdx.x * 64;
    __shared__ float T[64 * 68];

    const int tid = threadIdx.x;
    const int r   = tid >> 2;
    const int seg = tid & 3;

    const float* xb = x + ((size_t)b * Cc + c0) * Nn;
#pragma unroll
    for (int i = 0; i < 4; ++i) {
        float4 v = *reinterpret_cast<const float4*>(&xb[(size_t)r * Nn + n0 + seg * 16 + i * 4]);
        *reinterpret_cast<float4*>(&T[r * 68 + seg * 16 + i * 4]) = v;
    }
    __syncthreads();

    short* oh = xt + ((size_t)b * Nn + n0 + r) * Cc + c0;
#pragma unroll
    for (int i = 0; i < 4; ++i) {
        bf16x4 hv;
#pragma unroll
        for (int j = 0; j < 4; ++j)
            hv[j] = f2b(T[(seg * 16 + i * 4 + j) * 68 + r]);
        *reinterpret_cast<bf16x4*>(&oh[seg * 16 + i * 4]) = hv;
    }
}

// ---------------------------------------------------------------------------
// Single-pass bf16 MFMA GEMM, 2-phase LDS dbuf, global_load_lds staging.
// MODE 0 (QKV): m<768 -> Yqk token-major (B,N,768) bf16 (Q pre-scaled SCL2);
//   m>=768 -> Yv (B,384,N) bf16, columns sigma-permuted per 64-n group.
// MODE 1 (PROJ): fp32 out + bias.   (unchanged from R21/R22)
// ---------------------------------------------------------------------------
template <int MODE>
__global__ __launch_bounds__(256) void gemm_bf16(const short* __restrict__ Whi,
                                                 const short* __restrict__ Xh,
                                                 short* __restrict__ Yqk,
                                                 short* __restrict__ Yv,
                                                 float* __restrict__ Yf,
                                                 const float* __restrict__ bias,
                                                 int M, int K, int NN)
{
    const int b  = blockIdx.z;
    const int m0 = blockIdx.y * 128;
    const int n0 = blockIdx.x * 128;
    const short* Xb = Xh + (size_t)b * NN * K;

    constexpr int BUFS = 8192;    // shorts per buffer (2 tiles)
    constexpr int OA = 0;
    constexpr int OB = 4096;
    __shared__ __align__(16) short smem[17408];

    const int tid  = threadIdx.x;
    const int lane = tid & 63;
    const int wave = tid >> 6;
    const int c    = lane & 15;
    const int h4   = lane >> 4;
    const int wr   = wave >> 1;
    const int wc   = wave & 1;

    const int sq   = ((tid & 3) ^ ((tid >> 3) & 3)) * 8;
    const int lds0 = wave * 512;
    const int lds1 = 2048 + wave * 512;

    const short* gW = Whi + (size_t)(m0 + (tid >> 2)) * K + sq;
    const short* gX = Xb + (size_t)(n0 + (tid >> 2)) * K + sq;
    const size_t rowskip = (size_t)64 * K;

    const int sw = (h4 ^ ((c >> 1) & 3)) * 8;

    f32x4 acc[4][4];
#pragma unroll
    for (int mi = 0; mi < 4; ++mi)
#pragma unroll
        for (int ni = 0; ni < 4; ++ni) acc[mi][ni] = 0.0f;

    gload16(gW,           smem + OA + lds0);
    gload16(gW + rowskip, smem + OA + lds1);
    gload16(gX,           smem + OB + lds0);
    gload16(gX + rowskip, smem + OB + lds1);
    __syncthreads();

    const int NT = K >> 5;   // 12
    for (int t = 0; t < NT; ++t) {
        short* cbuf = smem + (t & 1) * BUFS;

        if (t + 1 < NT) {
            short* nbuf = smem + ((t + 1) & 1) * BUFS;
            const int nk = (t + 1) * 32;
            gload16(gW + nk,           nbuf + OA + lds0);
            gload16(gW + rowskip + nk, nbuf + OA + lds1);
            gload16(gX + nk,           nbuf + OB + lds0);
            gload16(gX + rowskip + nk, nbuf + OB + lds1);
        }

        bf16x8 a[4], bb[4];
#pragma unroll
        for (int mi = 0; mi < 4; ++mi) {
            int row = wr * 64 + mi * 16 + c;
            a[mi] = *reinterpret_cast<const bf16x8*>(&cbuf[OA + row * 32 + sw]);
        }
#pragma unroll
        for (int ni = 0; ni < 4; ++ni) {
            int row = wc * 64 + ni * 16 + c;
            bb[ni] = *reinterpret_cast<const bf16x8*>(&cbuf[OB + row * 32 + sw]);
        }
        __builtin_amdgcn_s_setprio(1);
#pragma unroll
        for (int mi = 0; mi < 4; ++mi)
#pragma unroll
            for (int ni = 0; ni < 4; ++ni)
                acc[mi][ni] = __builtin_amdgcn_mfma_f32_16x16x32_bf16(a[mi], bb[ni], acc[mi][ni], 0, 0, 0);
        __builtin_amdgcn_s_setprio(0);

        __syncthreads();
    }

    if (MODE == 0) {
        if (m0 < 768) {
            const float qscale = (m0 < 384) ? SCL2 : 1.0f;
            short* Cs = smem;  // [128 n][136]
#pragma unroll
            for (int mi = 0; mi < 4; ++mi)
#pragma unroll
                for (int ni = 0; ni < 4; ++ni) {
                    int nl = wc * 64 + ni * 16 + c;
                    int cl = wr * 64 + mi * 16 + 4 * h4;
                    bf16x4 pk;
#pragma unroll
                    for (int r = 0; r < 4; ++r) pk[r] = f2b(acc[mi][ni][r] * qscale);
                    *reinterpret_cast<bf16x4*>(&Cs[nl * 136 + cl]) = pk;
                }
            __syncthreads();
#pragma unroll
            for (int l = 0; l < 8; ++l) {
                int u  = tid + l * 256;
                int nl = u >> 4, ch = u & 15;
                *reinterpret_cast<bf16x8*>(&Yqk[((size_t)b * NN + n0 + nl) * 768 + m0 + ch * 8]) =
                    *reinterpret_cast<const bf16x8*>(&Cs[nl * 136 + ch * 8]);
            }
        } else {
            short* Cs = smem;  // [128 ch][136]
#pragma unroll
            for (int mi = 0; mi < 4; ++mi)
#pragma unroll
                for (int ni = 0; ni < 4; ++ni) {
                    int npb = wc * 64 + 32 * (ni >> 1) + 8 * (c >> 2) + 4 * (ni & 1) + (c & 3);
#pragma unroll
                    for (int r = 0; r < 4; ++r) {
                        int ml = wr * 64 + mi * 16 + h4 * 4 + r;
                        Cs[ml * 136 + npb] = f2b(acc[mi][ni][r]);
                    }
                }
            __syncthreads();
            short* Yb = Yv + (size_t)b * Cc * NN;
            const int srow2 = tid >> 1;
            const int cseg  = (tid & 1) * 64;
#pragma unroll
            for (int i = 0; i < 8; ++i)
                *reinterpret_cast<bf16x8*>(&Yb[(size_t)(m0 - 768 + srow2) * NN + n0 + cseg + i * 8]) =
                    *reinterpret_cast<const bf16x8*>(&Cs[srow2 * 136 + cseg + i * 8]);
        }
    } else {
        float* Yb = Yf + (size_t)b * M * NN;
        float* Cf = reinterpret_cast<float*>(smem);
        const int mr2 = tid >> 2;
        const int seg = tid & 3;
#pragma unroll
        for (int half = 0; half < 2; ++half) {
            __syncthreads();
            if (wr == half) {
#pragma unroll
                for (int mi = 0; mi < 4; ++mi)
#pragma unroll
                    for (int ni = 0; ni < 4; ++ni)
#pragma unroll
                        for (int r = 0; r < 4; ++r) {
                            int ml = mi * 16 + h4 * 4 + r;
                            int nl = wc * 64 + ni * 16 + c;
                            Cf[ml * 132 + nl] = acc[mi][ni][r];
                        }
            }
            __syncthreads();
            float bv = bias ? bias[m0 + half * 64 + mr2] : 0.0f;
#pragma unroll
            for (int i = 0; i < 8; ++i) {
                float4 v = *reinterpret_cast<const float4*>(&Cf[mr2 * 132 + seg * 32 + i * 4]);
                v.x += bv; v.y += bv; v.z += bv; v.w += bv;
                *reinterpret_cast<float4*>(&Yb[(size_t)(m0 + half * 64 + mr2) * NN + n0 + seg * 32 + i * 4]) = v;
            }
        }
    }
}

// ---------------------------------------------------------------------------
// Hybrid MFMA flash attention, 2 q-sets/wave (R21 config) + 3-BUFFER COUNTED
// VMCNT PIPELINE (T4): stage tile t+2 while computing t; at the barrier wait
// only vmcnt(4) so tile t+2's loads stay in flight (tile t+1's, being older,
// are guaranteed drained).  Raw s_barrier (no vmcnt(0) drain) + sched_barrier.
// Per-wave loads equalized to exactly 4/tile (waves 2,3 duplicate waves 0,1's
// V rows 32-47 loads — identical data to identical addresses, benign).
// Ones-row lsum rows in all 3 buffers; XCD remap; sigma-pre-permuted V.
// Numerics bit-identical to R21.
// ---------------------------------------------------------------------------
__global__ __launch_bounds__(256, 3) void attn_mfma(const short* __restrict__ qk_t,
                                                    const short* __restrict__ v_cn,
                                                    short* __restrict__ aot)
{
    // XCD-aware decode: id%8 selects XCD under round-robin dispatch.
    const int id = blockIdx.x;           // 0..1023
    const int rx = id & 7;
    const int kk = id >> 3;              // 0..127
    const int bh = rx * 16 + (kk & 15);  // 0..127
    const int qt = kk >> 4;              // 0..7
    const int b  = bh >> 3;
    const int h  = bh & 7;
    const int n0 = qt * 128;

    __shared__ __align__(16) short smem[24576];  // 3 x (Ks 4096 + Vs 4096)

    const int tid  = threadIdx.x;
    const int lane = tid & 63;
    const int wave = tid >> 6;
    const int c    = lane & 15;
    const int h4   = lane >> 4;
    const int qb   = n0 + wave * 32;

    const short* Qb    = qk_t + ((size_t)b * Nn + qb) * 768 + h * HD;
    const short* Kbase = qk_t + (size_t)b * Nn * 768 + 384 + h * HD;
    const short* Vb    = v_cn + ((size_t)b * Cc + h * HD) * Nn;

    const bf16x8 z8 = {};

    // init Vs rows 48..63 in ALL THREE buffers: row 48 = 1.0, rest 0
    {
        int i0 = tid * 4;
        short v = (i0 < 64) ? (short)0x3F80 : (short)0;
        bf16x4 iv = {v, v, v, v};
        *reinterpret_cast<bf16x4*>(&smem[7168 + i0])  = iv;
        *reinterpret_cast<bf16x4*>(&smem[15360 + i0]) = iv;
        *reinterpret_cast<bf16x4*>(&smem[23552 + i0]) = iv;
    }

    // ---- Q fragments (loop-invariant, 2 sets) ----
    bf16x8 qf0[2], qf1[2];
#pragma unroll
    for (int s = 0; s < 2; ++s) {
        const short* qrow = Qb + (size_t)(s * 16 + c) * 768;
        qf0[s] = *reinterpret_cast<const bf16x8*>(qrow + 8 * h4);
        qf1[s] = (h4 < 2) ? *reinterpret_cast<const bf16x8*>(qrow + 32 + 8 * h4) : z8;
    }

    // staging indices (per-thread, tile-invariant)
    const int u0 = wave * 64 + lane;
    const int r0 = u0 >> 3;
    const int sc0 = ((u0 & 7) ^ (r0 & 7)) * 8;
    const int u1 = 256 + u0;
    const int r1 = u1 >> 3;
    const int sc1 = ((u1 & 7) ^ (r1 & 7)) * 8;
    // equalized V rows 32..47 (waves 2,3 duplicate waves 0,1)
    const int u1v = 256 + (wave & 1) * 64 + lane;
    const int r1v = u1v >> 3;
    const int sc1v = ((u1v & 7) ^ (r1v & 7)) * 8;
    const int vdst1 = 4096 + 2048 + (wave & 1) * 512;

    const int cs8 = c & 7;
    const int ks0 = (h4 ^ cs8) * 8;
    const int ks1 = ((4 + h4) ^ cs8) * 8;

    f32x4 o[2][3];
#pragma unroll
    for (int s = 0; s < 2; ++s)
#pragma unroll
        for (int jd = 0; jd < 3; ++jd) o[s][jd] = 0.0f;
    f32x4 o3[2];
    o3[0] = 0.0f; o3[1] = 0.0f;

#define STAGE(BUF, MT)                                                          \
    gload16(Kbase + (size_t)((MT) + r0) * 768 + sc0, (BUF) + wave * 512);       \
    gload16(Kbase + (size_t)((MT) + r1) * 768 + sc1, (BUF) + 2048 + wave * 512);\
    gload16(Vb + (size_t)r0 * Nn + (MT) + sc0, (BUF) + 4096 + wave * 512);      \
    gload16(Vb + (size_t)r1v * Nn + (MT) + sc1v, (BUF) + vdst1);

    short* cur = smem;
    short* nxt = smem + 8192;
    short* fut = smem + 16384;

    // prologue: stage tiles 0 and 1 (8 loads/wave); drain tile 0's (vmcnt(4))
    STAGE(cur, 0);
    STAGE(nxt, 64);
    asm volatile("s_waitcnt vmcnt(4) lgkmcnt(0)" ::: "memory");
    __builtin_amdgcn_s_barrier();
    __builtin_amdgcn_sched_barrier(0);

    for (int t = 0; t < 16; ++t) {
        // stage tile t+2 into fut (4 loads/wave)
        if (t + 2 < 16) { STAGE(fut, (t + 2) * 64); }

        const short* Ks = cur;
        const short* Vs = cur + 4096;

        // ---- QK^T (K frags shared by both sets) ----
        f32x4 s4a[4], s4b[4];
#pragma unroll
        for (int j = 0; j < 4; ++j) { s4a[j] = 0.0f; s4b[j] = 0.0f; }
        __builtin_amdgcn_s_setprio(1);
#pragma unroll
        for (int j = 0; j < 4; ++j) {
            int kr = (16 * j + c) * 64;
            bf16x8 kc0 = *reinterpret_cast<const bf16x8*>(&Ks[kr + ks0]);
            bf16x8 kc1 = *reinterpret_cast<const bf16x8*>(&Ks[kr + ks1]);
            s4a[j] = __builtin_amdgcn_mfma_f32_16x16x32_bf16(kc0, qf0[0], s4a[j], 0, 0, 0);
            s4a[j] = __builtin_amdgcn_mfma_f32_16x16x32_bf16(kc1, qf1[0], s4a[j], 0, 0, 0);
            s4b[j] = __builtin_amdgcn_mfma_f32_16x16x32_bf16(kc0, qf0[1], s4b[j], 0, 0, 0);
            s4b[j] = __builtin_amdgcn_mfma_f32_16x16x32_bf16(kc1, qf1[1], s4b[j], 0, 0, 0);
        }
        __builtin_amdgcn_s_setprio(0);

        // ---- softmax-lite + pack P (sigma order), both sets ----
        bf16x8 pa[2][2];
        {
            float p[4][4];
#pragma unroll
            for (int j = 0; j < 4; ++j)
#pragma unroll
                for (int r = 0; r < 4; ++r)
                    p[j][r] = exp2f(s4a[j][r]);
#pragma unroll
            for (int r = 0; r < 4; ++r) {
                pa[0][0][r]     = f2b(p[0][r]);
                pa[0][0][4 + r] = f2b(p[1][r]);
                pa[0][1][r]     = f2b(p[2][r]);
                pa[0][1][4 + r] = f2b(p[3][r]);
            }
        }
        {
            float p[4][4];
#pragma unroll
            for (int j = 0; j < 4; ++j)
#pragma unroll
                for (int r = 0; r < 4; ++r)
                    p[j][r] = exp2f(s4b[j][r]);
#pragma unroll
            for (int r = 0; r < 4; ++r) {
                pa[1][0][r]     = f2b(p[0][r]);
                pa[1][0][4 + r] = f2b(p[1][r]);
                pa[1][1][r]     = f2b(p[2][r]);
                pa[1][1][4 + r] = f2b(p[3][r]);
            }
        }

        // ---- PV (jd 0..2) + ones-row lsum (jd 3): single b128 V frags ----
        __builtin_amdgcn_s_setprio(1);
#pragma unroll
        for (int jd = 0; jd < 4; ++jd) {
            int vr = (16 * jd + c) * 64;
            bf16x8 vf0 = *reinterpret_cast<const bf16x8*>(&Vs[vr + ks0]);
            bf16x8 vf1 = *reinterpret_cast<const bf16x8*>(&Vs[vr + ks1]);
            if (jd < 3) {
                o[0][jd] = __builtin_amdgcn_mfma_f32_16x16x32_bf16(vf0, pa[0][0], o[0][jd], 0, 0, 0);
                o[0][jd] = __builtin_amdgcn_mfma_f32_16x16x32_bf16(vf1, pa[0][1], o[0][jd], 0, 0, 0);
                o[1][jd] = __builtin_amdgcn_mfma_f32_16x16x32_bf16(vf0, pa[1][0], o[1][jd], 0, 0, 0);
                o[1][jd] = __builtin_amdgcn_mfma_f32_16x16x32_bf16(vf1, pa[1][1], o[1][jd], 0, 0, 0);
            } else {
                o3[0] = __builtin_amdgcn_mfma_f32_16x16x32_bf16(vf0, pa[0][0], o3[0], 0, 0, 0);
                o3[0] = __builtin_amdgcn_mfma_f32_16x16x32_bf16(vf1, pa[0][1], o3[0], 0, 0, 0);
                o3[1] = __builtin_amdgcn_mfma_f32_16x16x32_bf16(vf0, pa[1][0], o3[1], 0, 0, 0);
                o3[1] = __builtin_amdgcn_mfma_f32_16x16x32_bf16(vf1, pa[1][1], o3[1], 0, 0, 0);
            }
        }
        __builtin_amdgcn_s_setprio(0);

        // ---- counted-vmcnt barrier: keep fut's 4 loads in flight ----
        if (t + 2 < 16) asm volatile("s_waitcnt vmcnt(4)" ::: "memory");
        else            asm volatile("s_waitcnt vmcnt(0)" ::: "memory");
        __builtin_amdgcn_s_barrier();
        __builtin_amdgcn_sched_barrier(0);

        short* tmp = cur; cur = nxt; nxt = fut; fut = tmp;
    }
#undef STAGE

    // ---- epilogue: lsum broadcast from h4==0 lanes, normalize, bf16 out ----
#pragma unroll
    for (int set = 0; set < 2; ++set) {
        float ls = __shfl(o3[set][0], c);
        float linv = 1.0f / ls;
        size_t rowoff = ((size_t)b * Nn + qb + set * 16 + c) * Cc + h * HD;
#pragma unroll
        for (int jd = 0; jd < 3; ++jd) {
            bf16x4 hv;
#pragma unroll
            for (int r = 0; r < 4; ++r)
                hv[r] = f2b(o[set][jd][r] * linv);
            *reinterpret_cast<bf16x4*>(&aot[rowoff + 16 * jd + 4 * h4]) = hv;
        }
    }
}

// ---------------------------------------------------------------------------
extern "C" void kernel_launch(void* const* d_in, const int* in_sizes, int n_in,
                              void* d_out, int out_size, void* d_ws, size_t ws_size,
                              hipStream_t stream)
{
    const float* x      = (const float*)d_in[0];
    const float* w_qkv  = (const float*)d_in[1];
    const float* w_proj = (const float*)d_in[2];
    const float* b_proj = (const float*)d_in[3];
    float* out = (float*)d_out;

    short* ws = (short*)d_ws;
    const size_t XT = (size_t)Bn * Nn * Cc;            // 6291456
    short* xt    = ws;
    short* wq_hi = xt + XT;
    short* wp_hi = wq_hi + (size_t)3 * Cc * Cc;
    short* qk_t  = wp_hi + (size_t)Cc * Cc;            // (B, N, 768)
    short* v_cn  = qk_t + (size_t)Bn * Nn * 768;       // (B, 384, N) sigma-perm
    short* aot   = v_cn + XT;                          // (B, N, C) bf16

    // 0) weight cast (fused) + x transpose/cast
    {
        int n1 = 3 * Cc * Cc, n2 = Cc * Cc;
        int units = (n1 + n2) / 4;
        conv_cast2<<<(units + 255) / 256, 256, 0, stream>>>(
            w_qkv, wq_hi, n1, w_proj, wp_hi, n2);
    }
    prep_xt<<<dim3(Nn / 64, Cc / 64, Bn), 256, 0, stream>>>(x, xt);

    // 1) QKV GEMM (single-pass bf16, 2-phase dbuf) -> qk_t + sigma-permuted v_cn
    gemm_bf16<0><<<dim3(Nn / 128, (3 * Cc) / 128, Bn), 256, 0, stream>>>(
        wq_hi, xt, qk_t, v_cn, nullptr, nullptr, 3 * Cc, Cc, Nn);

    // 2) Hybrid attention (2 sets/wave, 3-buffer counted-vmcnt pipeline)
    attn_mfma<<<1024, 256, 0, stream>>>(qk_t, v_cn, aot);

    // 3) Projection GEMM (single-pass bf16, 2-phase dbuf, fp32 out + bias)
    gemm_bf16<1><<<dim3(Nn / 128, Cc / 128, Bn), 256, 0, stream>>>(
        wp_hi, aot, nullptr, nullptr, out, b_proj, Cc, Cc, Nn);
}

// Round 24
// 112.764 us; speedup vs baseline: 1.0081x; 1.0081x over previous
//
#include <hip/hip_runtime.h>
#include <hip/hip_bf16.h>
#include <math.h>

// Problem constants
constexpr int Bn     = 16;    // batch
constexpr int Cc     = 384;   // channels
constexpr int Nn     = 1024;  // tokens (32*32)
constexpr int NHEADS = 8;
constexpr int HD     = 48;    // head dim
constexpr float SCALE = 0.14433756729740643f; // 48^-0.5
constexpr float SCL2  = 0.14433756729740643f * 1.4426950408889634f; // SCALE*log2(e)

using bf16x8 = __attribute__((ext_vector_type(8))) short;
using bf16x4 = __attribute__((ext_vector_type(4))) short;
using f32x4  = __attribute__((ext_vector_type(4))) float;

__device__ inline short f2b(float f) {
    __hip_bfloat16 h = __float2bfloat16(f);
    return *reinterpret_cast<short*>(&h);
}

// async global->LDS, 16B per lane; LDS dest = wave-uniform base + lane*16B
__device__ __forceinline__ void gload16(const short* g, short* l) {
    __builtin_amdgcn_global_load_lds(
        (const __attribute__((address_space(1))) void*)(g),
        (__attribute__((address_space(3))) void*)(l),
        16, 0, 0);
}

// ---------------------------------------------------------------------------
// Fused fp32 -> bf16 cast for BOTH weight tensors.
// ---------------------------------------------------------------------------
__global__ __launch_bounds__(256) void conv_cast2(const float* __restrict__ in1,
                                                  short* __restrict__ hi1, int n1,
                                                  const float* __restrict__ in2,
                                                  short* __restrict__ hi2, int n2)
{
    int u = blockIdx.x * 256 + threadIdx.x;
    const float* in; short* hi; int i;
    if (u * 4 < n1) { in = in1; hi = hi1; i = u * 4; }
    else {
        i = u * 4 - n1;
        if (i >= n2) return;
        in = in2; hi = hi2;
    }
    float4 v = *reinterpret_cast<const float4*>(&in[i]);
    bf16x4 h = { f2b(v.x), f2b(v.y), f2b(v.z), f2b(v.w) };
    *reinterpret_cast<bf16x4*>(&hi[i]) = h;
}

// ---------------------------------------------------------------------------
// x (B, C, N) fp32 -> x^T (B, N, C) bf16.  64x64 tile via LDS.
// ---------------------------------------------------------------------------
__global__ __launch_bounds__(256) void prep_xt(const float* __restrict__ x,
                                               short* __restrict__ xt)
{
    const int b  = blockIdx.z;
    const int c0 = blockIdx.y * 64;
    const int n0 = blockIdx.x * 64;
    __shared__ float T[64 * 68];

    const int tid = threadIdx.x;
    const int r   = tid >> 2;
    const int seg = tid & 3;

    const float* xb = x + ((size_t)b * Cc + c0) * Nn;
#pragma unroll
    for (int i = 0; i < 4; ++i) {
        float4 v = *reinterpret_cast<const float4*>(&xb[(size_t)r * Nn + n0 + seg * 16 + i * 4]);
        *reinterpret_cast<float4*>(&T[r * 68 + seg * 16 + i * 4]) = v;
    }
    __syncthreads();

    short* oh = xt + ((size_t)b * Nn + n0 + r) * Cc + c0;
#pragma unroll
    for (int i = 0; i < 4; ++i) {
        bf16x4 hv;
#pragma unroll
        for (int j = 0; j < 4; ++j)
            hv[j] = f2b(T[(seg * 16 + i * 4 + j) * 68 + r]);
        *reinterpret_cast<bf16x4*>(&oh[seg * 16 + i * 4]) = hv;
    }
}

// ---------------------------------------------------------------------------
// Single-pass bf16 MFMA GEMM, 2-phase LDS dbuf, global_load_lds staging.
// MODE 0 (QKV): m<768 -> Yqk token-major (B,N,768) bf16 (Q pre-scaled SCL2);
//   m>=768 -> Yv (B,384,N) bf16, columns sigma-permuted per 64-n group.
// MODE 1 (PROJ): fp32 out + bias.
// ---------------------------------------------------------------------------
template <int MODE>
__global__ __launch_bounds__(256) void gemm_bf16(const short* __restrict__ Whi,
                                                 const short* __restrict__ Xh,
                                                 short* __restrict__ Yqk,
                                                 short* __restrict__ Yv,
                                                 float* __restrict__ Yf,
                                                 const float* __restrict__ bias,
                                                 int M, int K, int NN)
{
    const int b  = blockIdx.z;
    const int m0 = blockIdx.y * 128;
    const int n0 = blockIdx.x * 128;
    const short* Xb = Xh + (size_t)b * NN * K;

    constexpr int BUFS = 8192;    // shorts per buffer (2 tiles)
    constexpr int OA = 0;
    constexpr int OB = 4096;
    __shared__ __align__(16) short smem[17408];

    const int tid  = threadIdx.x;
    const int lane = tid & 63;
    const int wave = tid >> 6;
    const int c    = lane & 15;
    const int h4   = lane >> 4;
    const int wr   = wave >> 1;
    const int wc   = wave & 1;

    const int sq   = ((tid & 3) ^ ((tid >> 3) & 3)) * 8;
    const int lds0 = wave * 512;
    const int lds1 = 2048 + wave * 512;

    const short* gW = Whi + (size_t)(m0 + (tid >> 2)) * K + sq;
    const short* gX = Xb + (size_t)(n0 + (tid >> 2)) * K + sq;
    const size_t rowskip = (size_t)64 * K;

    const int sw = (h4 ^ ((c >> 1) & 3)) * 8;

    f32x4 acc[4][4];
#pragma unroll
    for (int mi = 0; mi < 4; ++mi)
#pragma unroll
        for (int ni = 0; ni < 4; ++ni) acc[mi][ni] = 0.0f;

    gload16(gW,           smem + OA + lds0);
    gload16(gW + rowskip, smem + OA + lds1);
    gload16(gX,           smem + OB + lds0);
    gload16(gX + rowskip, smem + OB + lds1);
    __syncthreads();

    const int NT = K >> 5;   // 12
    for (int t = 0; t < NT; ++t) {
        short* cbuf = smem + (t & 1) * BUFS;

        if (t + 1 < NT) {
            short* nbuf = smem + ((t + 1) & 1) * BUFS;
            const int nk = (t + 1) * 32;
            gload16(gW + nk,           nbuf + OA + lds0);
            gload16(gW + rowskip + nk, nbuf + OA + lds1);
            gload16(gX + nk,           nbuf + OB + lds0);
            gload16(gX + rowskip + nk, nbuf + OB + lds1);
        }

        bf16x8 a[4], bb[4];
#pragma unroll
        for (int mi = 0; mi < 4; ++mi) {
            int row = wr * 64 + mi * 16 + c;
            a[mi] = *reinterpret_cast<const bf16x8*>(&cbuf[OA + row * 32 + sw]);
        }
#pragma unroll
        for (int ni = 0; ni < 4; ++ni) {
            int row = wc * 64 + ni * 16 + c;
            bb[ni] = *reinterpret_cast<const bf16x8*>(&cbuf[OB + row * 32 + sw]);
        }
        __builtin_amdgcn_s_setprio(1);
#pragma unroll
        for (int mi = 0; mi < 4; ++mi)
#pragma unroll
            for (int ni = 0; ni < 4; ++ni)
                acc[mi][ni] = __builtin_amdgcn_mfma_f32_16x16x32_bf16(a[mi], bb[ni], acc[mi][ni], 0, 0, 0);
        __builtin_amdgcn_s_setprio(0);

        __syncthreads();
    }

    if (MODE == 0) {
        if (m0 < 768) {
            const float qscale = (m0 < 384) ? SCL2 : 1.0f;
            short* Cs = smem;  // [128 n][136]
#pragma unroll
            for (int mi = 0; mi < 4; ++mi)
#pragma unroll
                for (int ni = 0; ni < 4; ++ni) {
                    int nl = wc * 64 + ni * 16 + c;
                    int cl = wr * 64 + mi * 16 + 4 * h4;
                    bf16x4 pk;
#pragma unroll
                    for (int r = 0; r < 4; ++r) pk[r] = f2b(acc[mi][ni][r] * qscale);
                    *reinterpret_cast<bf16x4*>(&Cs[nl * 136 + cl]) = pk;
                }
            __syncthreads();
#pragma unroll
            for (int l = 0; l < 8; ++l) {
                int u  = tid + l * 256;
                int nl = u >> 4, ch = u & 15;
                *reinterpret_cast<bf16x8*>(&Yqk[((size_t)b * NN + n0 + nl) * 768 + m0 + ch * 8]) =
                    *reinterpret_cast<const bf16x8*>(&Cs[nl * 136 + ch * 8]);
            }
        } else {
            short* Cs = smem;  // [128 ch][136]
#pragma unroll
            for (int mi = 0; mi < 4; ++mi)
#pragma unroll
                for (int ni = 0; ni < 4; ++ni) {
                    int npb = wc * 64 + 32 * (ni >> 1) + 8 * (c >> 2) + 4 * (ni & 1) + (c & 3);
#pragma unroll
                    for (int r = 0; r < 4; ++r) {
                        int ml = wr * 64 + mi * 16 + h4 * 4 + r;
                        Cs[ml * 136 + npb] = f2b(acc[mi][ni][r]);
                    }
                }
            __syncthreads();
            short* Yb = Yv + (size_t)b * Cc * NN;
            const int srow2 = tid >> 1;
            const int cseg  = (tid & 1) * 64;
#pragma unroll
            for (int i = 0; i < 8; ++i)
                *reinterpret_cast<bf16x8*>(&Yb[(size_t)(m0 - 768 + srow2) * NN + n0 + cseg + i * 8]) =
                    *reinterpret_cast<const bf16x8*>(&Cs[srow2 * 136 + cseg + i * 8]);
        }
    } else {
        float* Yb = Yf + (size_t)b * M * NN;
        float* Cf = reinterpret_cast<float*>(smem);
        const int mr2 = tid >> 2;
        const int seg = tid & 3;
#pragma unroll
        for (int half = 0; half < 2; ++half) {
            __syncthreads();
            if (wr == half) {
#pragma unroll
                for (int mi = 0; mi < 4; ++mi)
#pragma unroll
                    for (int ni = 0; ni < 4; ++ni)
#pragma unroll
                        for (int r = 0; r < 4; ++r) {
                            int ml = mi * 16 + h4 * 4 + r;
                            int nl = wc * 64 + ni * 16 + c;
                            Cf[ml * 132 + nl] = acc[mi][ni][r];
                        }
            }
            __syncthreads();
            float bv = bias ? bias[m0 + half * 64 + mr2] : 0.0f;
#pragma unroll
            for (int i = 0; i < 8; ++i) {
                float4 v = *reinterpret_cast<const float4*>(&Cf[mr2 * 132 + seg * 32 + i * 4]);
                v.x += bv; v.y += bv; v.z += bv; v.w += bv;
                *reinterpret_cast<float4*>(&Yb[(size_t)(m0 + half * 64 + mr2) * NN + n0 + seg * 32 + i * 4]) = v;
            }
        }
    }
}

// ---------------------------------------------------------------------------
// Hybrid MFMA flash attention (best-measured R21 config): 2 q-sets/wave,
// 128-q blocks (grid 1024), global_load_lds staging, 2-phase K/V dbuf,
// ones-row lsum on the matrix pipe, XCD-aware 1D remap, sigma-pre-permuted V
// (single conflict-free b128 frags).
// ---------------------------------------------------------------------------
__global__ __launch_bounds__(256, 4) void attn_mfma(const short* __restrict__ qk_t,
                                                    const short* __restrict__ v_cn,
                                                    short* __restrict__ aot)
{
    // XCD-aware decode: id%8 selects XCD under round-robin dispatch.
    const int id = blockIdx.x;           // 0..1023
    const int rx = id & 7;
    const int kk = id >> 3;              // 0..127
    const int bh = rx * 16 + (kk & 15);  // 0..127
    const int qt = kk >> 4;              // 0..7
    const int b  = bh >> 3;
    const int h  = bh & 7;
    const int n0 = qt * 128;

    __shared__ __align__(16) short smem[16384];  // 2 x (Ks 4096 + Vs 4096)

    const int tid  = threadIdx.x;
    const int lane = tid & 63;
    const int wave = tid >> 6;
    const int c    = lane & 15;
    const int h4   = lane >> 4;
    const int qb   = n0 + wave * 32;

    const short* Qb    = qk_t + ((size_t)b * Nn + qb) * 768 + h * HD;
    const short* Kbase = qk_t + (size_t)b * Nn * 768 + 384 + h * HD;
    const short* Vb    = v_cn + ((size_t)b * Cc + h * HD) * Nn;

    const bf16x8 z8 = {};

    // init Vs rows 48..63 in BOTH buffers: row 48 = 1.0, rows 49..63 = 0
    {
        int i0 = tid * 4;
        short v = (i0 < 64) ? (short)0x3F80 : (short)0;
        bf16x4 iv = {v, v, v, v};
        *reinterpret_cast<bf16x4*>(&smem[4096 + 3072 + i0]) = iv;
        *reinterpret_cast<bf16x4*>(&smem[12288 + 3072 + i0]) = iv;
    }

    // ---- Q fragments (loop-invariant, 2 sets) ----
    bf16x8 qf0[2], qf1[2];
#pragma unroll
    for (int s = 0; s < 2; ++s) {
        const short* qrow = Qb + (size_t)(s * 16 + c) * 768;
        qf0[s] = *reinterpret_cast<const bf16x8*>(qrow + 8 * h4);
        qf1[s] = (h4 < 2) ? *reinterpret_cast<const bf16x8*>(qrow + 32 + 8 * h4) : z8;
    }

    const int u0 = wave * 64 + lane;
    const int r0 = u0 >> 3;
    const int sc0 = ((u0 & 7) ^ (r0 & 7)) * 8;
    const int u1 = 256 + u0;
    const int r1 = u1 >> 3;
    const int sc1 = ((u1 & 7) ^ (r1 & 7)) * 8;

    const int cs8 = c & 7;
    const int ks0 = (h4 ^ cs8) * 8;
    const int ks1 = ((4 + h4) ^ cs8) * 8;

    f32x4 o[2][3];
#pragma unroll
    for (int s = 0; s < 2; ++s)
#pragma unroll
        for (int jd = 0; jd < 3; ++jd) o[s][jd] = 0.0f;
    f32x4 o3[2];
    o3[0] = 0.0f; o3[1] = 0.0f;

    // ---- prologue: stage tile 0 into buffer 0 ----
    {
        short* Ksb = smem;
        short* Vsb = smem + 4096;
        gload16(Kbase + (size_t)r0 * 768 + sc0, Ksb + wave * 512);
        gload16(Kbase + (size_t)r1 * 768 + sc1, Ksb + 2048 + wave * 512);
        gload16(Vb + (size_t)r0 * Nn + sc0, Vsb + wave * 512);
        if (wave < 2)
            gload16(Vb + (size_t)r1 * Nn + sc1, Vsb + 2048 + wave * 512);
    }
    __syncthreads();

    for (int t = 0; t < 16; ++t) {
        const short* Ks = smem + (t & 1) * 8192;
        const short* Vs = Ks + 4096;

        // prefetch next tile into the other buffer FIRST
        if (t + 1 < 16) {
            short* Ksn = smem + ((t + 1) & 1) * 8192;
            short* Vsn = Ksn + 4096;
            const int mn = (t + 1) * 64;
            gload16(Kbase + (size_t)(mn + r0) * 768 + sc0, Ksn + wave * 512);
            gload16(Kbase + (size_t)(mn + r1) * 768 + sc1, Ksn + 2048 + wave * 512);
            gload16(Vb + (size_t)r0 * Nn + mn + sc0, Vsn + wave * 512);
            if (wave < 2)
                gload16(Vb + (size_t)r1 * Nn + mn + sc1, Vsn + 2048 + wave * 512);
        }

        // ---- QK^T (K frags shared by both sets) ----
        f32x4 s4a[4], s4b[4];
#pragma unroll
        for (int j = 0; j < 4; ++j) { s4a[j] = 0.0f; s4b[j] = 0.0f; }
        __builtin_amdgcn_s_setprio(1);
#pragma unroll
        for (int j = 0; j < 4; ++j) {
            int kr = (16 * j + c) * 64;
            bf16x8 kc0 = *reinterpret_cast<const bf16x8*>(&Ks[kr + ks0]);
            bf16x8 kc1 = *reinterpret_cast<const bf16x8*>(&Ks[kr + ks1]);
            s4a[j] = __builtin_amdgcn_mfma_f32_16x16x32_bf16(kc0, qf0[0], s4a[j], 0, 0, 0);
            s4a[j] = __builtin_amdgcn_mfma_f32_16x16x32_bf16(kc1, qf1[0], s4a[j], 0, 0, 0);
            s4b[j] = __builtin_amdgcn_mfma_f32_16x16x32_bf16(kc0, qf0[1], s4b[j], 0, 0, 0);
            s4b[j] = __builtin_amdgcn_mfma_f32_16x16x32_bf16(kc1, qf1[1], s4b[j], 0, 0, 0);
        }
        __builtin_amdgcn_s_setprio(0);

        // ---- softmax-lite + pack P (sigma order), both sets ----
        bf16x8 pa[2][2];
        {
            float p[4][4];
#pragma unroll
            for (int j = 0; j < 4; ++j)
#pragma unroll
                for (int r = 0; r < 4; ++r)
                    p[j][r] = exp2f(s4a[j][r]);
#pragma unroll
            for (int r = 0; r < 4; ++r) {
                pa[0][0][r]     = f2b(p[0][r]);
                pa[0][0][4 + r] = f2b(p[1][r]);
                pa[0][1][r]     = f2b(p[2][r]);
                pa[0][1][4 + r] = f2b(p[3][r]);
            }
        }
        {
            float p[4][4];
#pragma unroll
            for (int j = 0; j < 4; ++j)
#pragma unroll
                for (int r = 0; r < 4; ++r)
                    p[j][r] = exp2f(s4b[j][r]);
#pragma unroll
            for (int r = 0; r < 4; ++r) {
                pa[1][0][r]     = f2b(p[0][r]);
                pa[1][0][4 + r] = f2b(p[1][r]);
                pa[1][1][r]     = f2b(p[2][r]);
                pa[1][1][4 + r] = f2b(p[3][r]);
            }
        }

        // ---- PV (jd 0..2) + ones-row lsum (jd 3): single b128 V frags ----
        __builtin_amdgcn_s_setprio(1);
#pragma unroll
        for (int jd = 0; jd < 4; ++jd) {
            int vr = (16 * jd + c) * 64;
            bf16x8 vf0 = *reinterpret_cast<const bf16x8*>(&Vs[vr + ks0]);
            bf16x8 vf1 = *reinterpret_cast<const bf16x8*>(&Vs[vr + ks1]);
            if (jd < 3) {
                o[0][jd] = __builtin_amdgcn_mfma_f32_16x16x32_bf16(vf0, pa[0][0], o[0][jd], 0, 0, 0);
                o[0][jd] = __builtin_amdgcn_mfma_f32_16x16x32_bf16(vf1, pa[0][1], o[0][jd], 0, 0, 0);
                o[1][jd] = __builtin_amdgcn_mfma_f32_16x16x32_bf16(vf0, pa[1][0], o[1][jd], 0, 0, 0);
                o[1][jd] = __builtin_amdgcn_mfma_f32_16x16x32_bf16(vf1, pa[1][1], o[1][jd], 0, 0, 0);
            } else {
                o3[0] = __builtin_amdgcn_mfma_f32_16x16x32_bf16(vf0, pa[0][0], o3[0], 0, 0, 0);
                o3[0] = __builtin_amdgcn_mfma_f32_16x16x32_bf16(vf1, pa[0][1], o3[0], 0, 0, 0);
                o3[1] = __builtin_amdgcn_mfma_f32_16x16x32_bf16(vf0, pa[1][0], o3[1], 0, 0, 0);
                o3[1] = __builtin_amdgcn_mfma_f32_16x16x32_bf16(vf1, pa[1][1], o3[1], 0, 0, 0);
            }
        }
        __builtin_amdgcn_s_setprio(0);

        __syncthreads();   // drains prefetch + protects buffer reuse
    }

    // ---- epilogue: lsum broadcast from h4==0 lanes, normalize, bf16 out ----
#pragma unroll
    for (int set = 0; set < 2; ++set) {
        float ls = __shfl(o3[set][0], c);
        float linv = 1.0f / ls;
        size_t rowoff = ((size_t)b * Nn + qb + set * 16 + c) * Cc + h * HD;
#pragma unroll
        for (int jd = 0; jd < 3; ++jd) {
            bf16x4 hv;
#pragma unroll
            for (int r = 0; r < 4; ++r)
                hv[r] = f2b(o[set][jd][r] * linv);
            *reinterpret_cast<bf16x4*>(&aot[rowoff + 16 * jd + 4 * h4]) = hv;
        }
    }
}

// ---------------------------------------------------------------------------
extern "C" void kernel_launch(void* const* d_in, const int* in_sizes, int n_in,
                              void* d_out, int out_size, void* d_ws, size_t ws_size,
                              hipStream_t stream)
{
    const float* x      = (const float*)d_in[0];
    const float* w_qkv  = (const float*)d_in[1];
    const float* w_proj = (const float*)d_in[2];
    const float* b_proj = (const float*)d_in[3];
    float* out = (float*)d_out;

    short* ws = (short*)d_ws;
    const size_t XT = (size_t)Bn * Nn * Cc;            // 6291456
    short* xt    = ws;
    short* wq_hi = xt + XT;
    short* wp_hi = wq_hi + (size_t)3 * Cc * Cc;
    short* qk_t  = wp_hi + (size_t)Cc * Cc;            // (B, N, 768)
    short* v_cn  = qk_t + (size_t)Bn * Nn * 768;       // (B, 384, N) sigma-perm
    short* aot   = v_cn + XT;                          // (B, N, C) bf16

    // 0) weight cast (fused) + x transpose/cast
    {
        int n1 = 3 * Cc * Cc, n2 = Cc * Cc;
        int units = (n1 + n2) / 4;
        conv_cast2<<<(units + 255) / 256, 256, 0, stream>>>(
            w_qkv, wq_hi, n1, w_proj, wp_hi, n2);
    }
    prep_xt<<<dim3(Nn / 64, Cc / 64, Bn), 256, 0, stream>>>(x, xt);

    // 1) QKV GEMM (single-pass bf16, 2-phase dbuf) -> qk_t + sigma-permuted v_cn
    gemm_bf16<0><<<dim3(Nn / 128, (3 * Cc) / 128, Bn), 256, 0, stream>>>(
        wq_hi, xt, qk_t, v_cn, nullptr, nullptr, 3 * Cc, Cc, Nn);

    // 2) Hybrid attention (2 sets/wave, 2-phase dbuf — best measured config)
    attn_mfma<<<1024, 256, 0, stream>>>(qk_t, v_cn, aot);

    // 3) Projection GEMM (single-pass bf16, 2-phase dbuf, fp32 out + bias)
    gemm_bf16<1><<<dim3(Nn / 128, Cc / 128, Bn), 256, 0, stream>>>(
        wp_hi, aot, nullptr, nullptr, out, b_proj, Cc, Cc, Nn);
}